// Round 14
// baseline (415.115 us; speedup 1.0000x reference)
//
#include <hip/hip_runtime.h>

#define D 64
#define HW 32                   // half-width features
#define BK_SHIFT 6              // 64 nodes per bucket
#define BK_CAP 8192             // staged entries per bucket (mean ~1600)
#define NBLK 256                // radix pass blocks
#define PAD_SLACK 2048          // per-bucket col padding slack (64 nodes * <=32)

typedef unsigned int v4u __attribute__((ext_vector_type(4)));

__device__ __forceinline__ float bfbits2f(unsigned short b) {
    union { unsigned int u; float f; } c;
    c.u = ((unsigned int)b) << 16;
    return c.f;
}

__device__ __forceinline__ unsigned short f2bfbits(float f) {
    union { float f; unsigned int u; } c;
    c.f = f;
    unsigned int u = c.u;
    unsigned int lsb = (u >> 16) & 1u;
    u += 0x7fffu + lsb;           // round-to-nearest-even
    return (unsigned short)(u >> 16);
}

__device__ __forceinline__ float ldmix(const void* p, size_t i, int isf32) {
    return isf32 ? ((const float*)p)[i] : bfbits2f(((const unsigned short*)p)[i]);
}

// ---- dtype sniff -----------------------------------------------------------
__global__ void sniff_kernel(const unsigned short* __restrict__ W, int* __restrict__ flag) {
    int t = threadIdx.x;
    bool bad = false;
    for (int i = t; i < 256; i += 64) {
        float v = bfbits2f(W[i]);
        if (!(v == v) || fabsf(v) > 1e4f) bad = true;
    }
    unsigned long long m = __ballot(bad);
    if (t == 0) *flag = (m != 0ull) ? 1 : 0;
}

// ---- param conversion ------------------------------------------------------
#define OW1 0
#define OW2 4096
#define OW3 8192
#define OB1 12288
#define OB2 12352
#define OB3 12416
#define OG  12480
#define OBE 12544
#define OPA 12608

__global__ void cvt_params_kernel(const void* W1, const void* b1, const void* W2, const void* b2,
                                  const void* W3, const void* b3, const void* pa, const void* g,
                                  const void* be, const int* __restrict__ flag,
                                  float* __restrict__ P) {
    int isf = *flag;
    int t = threadIdx.x;                 // one block of 256
    for (int i = t; i < D * D; i += 256) {
        P[OW1 + i] = ldmix(W1, i, isf);
        P[OW2 + i] = ldmix(W2, i, isf);
        P[OW3 + i] = ldmix(W3, i, isf);
    }
    if (t < D) {
        P[OB1 + t] = ldmix(b1, t, isf);
        P[OB2 + t] = ldmix(b2, t, isf);
        P[OB3 + t] = ldmix(b3, t, isf);
        P[OG  + t] = ldmix(g,  t, isf);
        P[OBE + t] = ldmix(be, t, isf);
    }
    if (t == 0) P[OPA] = ldmix(pa, 0, isf);
}

// ---- deterministic two-pass radix binning (no global atomics) --------------
// H layout: H[bucket * NBLK + block]

__global__ void binA1_kernel(const int* __restrict__ dst, int E, int NB, int CH,
                             int* __restrict__ H) {
    __shared__ int h[1024];
    int t = threadIdx.x, bb = blockIdx.x;
    for (int i = t; i < NB; i += 256) h[i] = 0;
    __syncthreads();
    int beg = bb * CH, end = beg + CH; if (end > E) end = E;
    for (int e = beg + t; e < end; e += 256)
        atomicAdd(&h[dst[e] >> BK_SHIFT], 1);
    __syncthreads();
    for (int i = t; i < NB; i += 256) H[i * NBLK + bb] = h[i];
}

// per-bucket exclusive scan of the NBLK block-counts; T[b] = bucket total
__global__ void binA2_kernel(int* __restrict__ H, int* __restrict__ T) {
    __shared__ int ws[4];
    __shared__ int wx[4];
    int b = blockIdx.x, t = threadIdx.x;
    int lane = t & 63, wid = t >> 6;
    int v = H[b * NBLK + t];
    int incl = v;
#pragma unroll
    for (int off = 1; off < 64; off <<= 1) {
        int u = __shfl_up(incl, off, 64);
        if (lane >= off) incl += u;
    }
    if (lane == 63) ws[wid] = incl;
    __syncthreads();
    if (t == 0) {
        int s = 0;
#pragma unroll
        for (int j = 0; j < 4; ++j) { wx[j] = s; s += ws[j]; }
        T[b] = s;
    }
    __syncthreads();
    H[b * NBLK + t] = wx[wid] + incl - v;
}

// single-block scan of bucket totals -> bucket_beg; also zero-rows of tables
__global__ void binA3_kernel(const int* __restrict__ T, int* __restrict__ bucket_beg, int NB,
                             unsigned short* XsL1, unsigned short* XsH1,
                             unsigned short* XsL2, unsigned short* XsH2, int N) {
    __shared__ int tile[1024];
    int t = threadIdx.x;
    int v = (t < NB) ? T[t] : 0;
    tile[t] = v;
    __syncthreads();
    for (int off = 1; off < 1024; off <<= 1) {
        int add = (t >= off) ? tile[t - off] : 0;
        __syncthreads();
        tile[t] += add;
        __syncthreads();
    }
    if (t < NB) bucket_beg[t] = tile[t] - v;
    if (t == NB - 1) bucket_beg[NB] = tile[t];
    if (t < HW) {                            // zero row (index N) for pad edges
        XsL1[(size_t)N * HW + t] = 0;
        XsH1[(size_t)N * HW + t] = 0;
        XsL2[(size_t)N * HW + t] = 0;
        XsH2[(size_t)N * HW + t] = 0;
    }
}

// scatter edges into bucket-grouped tmp via LDS cursors (deterministic ranges)
__global__ void binA4_kernel(const int* __restrict__ src, const int* __restrict__ dst,
                             const int* __restrict__ H, const int* __restrict__ bucket_beg,
                             unsigned int* __restrict__ tmp, int E, int NB, int CH) {
    __shared__ int O[1024];
    int t = threadIdx.x, bb = blockIdx.x;
    for (int i = t; i < NB; i += 256) O[i] = bucket_beg[i] + H[i * NBLK + bb];
    __syncthreads();
    int beg = bb * CH, end = beg + CH; if (end > E) end = E;
    for (int e = beg + t; e < end; e += 256) {
        int d = dst[e];
        int p = atomicAdd(&O[d >> BK_SHIFT], 1);
        tmp[p] = ((unsigned int)src[e] << BK_SHIFT) | (unsigned int)(d & 63);
    }
}

// one block per bucket: per-node count + padded scan (self-slot + mult-32) +
// L2-local scatter + pad fill (first pad = SELF loop, rest = zero row N) +
// fused layer-1 prescale into split half-tables
__global__ void binB_kernel(const unsigned int* __restrict__ tmp, const int* __restrict__ bucket_beg,
                            int* __restrict__ row_beg, int* __restrict__ cnt,
                            float* __restrict__ dinv, int* __restrict__ col,
                            const void* __restrict__ X, const int* __restrict__ flag,
                            unsigned short* __restrict__ XsL, unsigned short* __restrict__ XsH,
                            int N) {
    __shared__ unsigned int ent[BK_CAP];
    __shared__ int lv[64], lpv[64], lpe[64], lcur[64];
    __shared__ float ldv[64];
    int b = blockIdx.x, t = threadIdx.x;
    int beg = bucket_beg[b], end = bucket_beg[b + 1];
    int colbase = beg + b * PAD_SLACK;
    int m = end - beg;
    bool staged = (m <= BK_CAP);
    if (t < 64) lv[t] = 0;
    __syncthreads();
    for (int i = t; i < m; i += 256) {
        unsigned int e = tmp[beg + i];
        if (staged) ent[i] = e;
        atomicAdd(&lv[e & 63u], 1);
    }
    __syncthreads();
    if (t < 64) {
        int v  = lv[t];
        int pv = (v + 1 + 31) & ~31;         // +1 self slot, padded to mult of 32
        int incl = pv;
#pragma unroll
        for (int off = 1; off < 64; off <<= 1) {
            int u = __shfl_up(incl, off, 64);
            if (t >= off) incl += u;
        }
        int pexcl = incl - pv;
        lpv[t]  = pv;
        lpe[t]  = pexcl;
        lcur[t] = pexcl;
        float dv = rsqrtf((float)(v + 1));
        ldv[t] = dv;
        int node = b * 64 + t;
        if (node < N) {
            row_beg[node] = colbase + pexcl;
            cnt[node]     = pv;              // padded count incl. self (loop bound)
            dinv[node]    = dv;
        }
    }
    __syncthreads();
    for (int i = t; i < m; i += 256) {
        unsigned int e = staged ? ent[i] : tmp[beg + i];
        int p = atomicAdd(&lcur[e & 63u], 1);
        col[colbase + p] = (int)(e >> BK_SHIFT);
    }
    // pad fill: slot v = SELF node (replaces explicit self-loop), rest zero row N
    for (int i = t; i < 64 * 32; i += 256) {
        int nl = i >> 5, j = i & 31;
        int idx = lv[nl] + j;
        if (idx < lpv[nl]) {
            int node = b * 64 + nl;
            col[colbase + lpe[nl] + idx] = (j == 0) ? node : N;
        }
    }
    // fused layer-1 prescale into split tables
    int isf = *flag;
    for (int i = t; i < 64 * 64; i += 256) {
        int nl = i >> 6, f = i & 63;
        int node = b * 64 + nl;
        if (node < N) {
            unsigned short v16 = f2bfbits(ldv[nl] * ldmix(X, (size_t)node * D + f, isf));
            if (f < HW) XsL[(size_t)node * HW + f] = v16;
            else        XsH[(size_t)node * HW + (f - HW)] = v16;
        }
    }
}

// ---- feature kernels -------------------------------------------------------

__device__ __forceinline__ void acc8(float* a, v4u v) {
    a[0] += bfbits2f((unsigned short)(v.x & 0xffffu));
    a[1] += bfbits2f((unsigned short)(v.x >> 16));
    a[2] += bfbits2f((unsigned short)(v.y & 0xffffu));
    a[3] += bfbits2f((unsigned short)(v.y >> 16));
    a[4] += bfbits2f((unsigned short)(v.z & 0xffffu));
    a[5] += bfbits2f((unsigned short)(v.z >> 16));
    a[6] += bfbits2f((unsigned short)(v.w & 0xffffu));
    a[7] += bfbits2f((unsigned short)(v.w >> 16));
}

// 64B-row load from a half-table (PLAIN: this is the L2-resident reuse data)
__device__ __forceinline__ v4u ldrow32(const unsigned short* __restrict__ Xt, int s, int sub) {
    return *((const v4u*)(Xt + ((size_t)s << 5)) + sub);
}

// half-feature gather: table rows are 64B (32 bf16). One wave covers 16 rows
// per load inst (4 lanes/row). Wave aggregates 2 nodes; first chunks of both
// issued back-to-back (4 row loads in flight). cnt includes the self slot.
__global__ void __launch_bounds__(256)
agg_half_kernel(const unsigned short* __restrict__ Xt,
                const int* __restrict__ row_beg, const int* __restrict__ cnt,
                const int* __restrict__ col, const float* __restrict__ dinv,
                unsigned short* __restrict__ Yh,   // Y + hoff, row stride D
                int n) {
    int t = threadIdx.x;
    int wid = t >> 6, lane = t & 63;
    int sub = lane & 3, slot = lane >> 2;       // sub: 16B chunk, slot: row 0..15
    int nodeA = blockIdx.x * 8 + wid * 2;
    int nodeB = nodeA + 1;
    if (nodeA >= n) return;
    bool vB = (nodeB < n);
    int begA = row_beg[nodeA], pcA = cnt[nodeA];
    int begB = vB ? row_beg[nodeB] : begA, pcB = vB ? cnt[nodeB] : 32;
    float dnA = dinv[nodeA], dnB = vB ? dinv[nodeB] : 0.f;
    float a[8], b[8];
#pragma unroll
    for (int j = 0; j < 8; ++j) { a[j] = 0.f; b[j] = 0.f; }
    // first 32-edge chunk of both nodes (always present)
    {
        const int* cA = col + begA;
        const int* cB = col + begB;
        int sA0 = __builtin_nontemporal_load(cA + slot);
        int sA1 = __builtin_nontemporal_load(cA + 16 + slot);
        int sB0 = __builtin_nontemporal_load(cB + slot);
        int sB1 = __builtin_nontemporal_load(cB + 16 + slot);
        v4u vA0 = ldrow32(Xt, sA0, sub);
        v4u vA1 = ldrow32(Xt, sA1, sub);
        v4u vB0 = ldrow32(Xt, sB0, sub);
        v4u vB1 = ldrow32(Xt, sB1, sub);
        acc8(a, vA0); acc8(a, vA1);
        acc8(b, vB0); acc8(b, vB1);
    }
    // tails (deg+1 > 32)
    for (int c = 32; c < pcA; c += 32) {
        const int* cA = col + begA + c;
        int s0 = __builtin_nontemporal_load(cA + slot);
        int s1 = __builtin_nontemporal_load(cA + 16 + slot);
        v4u v0 = ldrow32(Xt, s0, sub);
        v4u v1 = ldrow32(Xt, s1, sub);
        acc8(a, v0); acc8(a, v1);
    }
    for (int c = 32; c < pcB; c += 32) {
        const int* cB = col + begB + c;
        int s0 = __builtin_nontemporal_load(cB + slot);
        int s1 = __builtin_nontemporal_load(cB + 16 + slot);
        v4u v0 = ldrow32(Xt, s0, sub);
        v4u v1 = ldrow32(Xt, s1, sub);
        acc8(b, v0); acc8(b, v1);
    }
    // reduce over the 16 row-slots (lane bits 2..5; sub preserved)
#pragma unroll
    for (int off = 4; off < 64; off <<= 1) {
#pragma unroll
        for (int j = 0; j < 8; ++j) {
            a[j] += __shfl_xor(a[j], off, 64);
            b[j] += __shfl_xor(b[j], off, 64);
        }
    }
    // slot 0 lanes write node A's 64B half-row; slot 1 lanes write node B's
    const float* sel = (slot == 1) ? b : a;
    float dn = (slot == 1) ? dnB : dnA;
    unsigned int pw[4];
#pragma unroll
    for (int j = 0; j < 4; ++j)
        pw[j] = (unsigned int)f2bfbits(dn * sel[2 * j]) |
                ((unsigned int)f2bfbits(dn * sel[2 * j + 1]) << 16);
    v4u w; w.x = pw[0]; w.y = pw[1]; w.z = pw[2]; w.w = pw[3];
    if (slot == 0)
        __builtin_nontemporal_store(w, (v4u*)(Yh + ((size_t)nodeA << 6)) + sub);
    else if (slot == 1 && vB)
        __builtin_nontemporal_store(w, (v4u*)(Yh + ((size_t)nodeB << 6)) + sub);
}

// unfused wave GEMM: 2 nodes/wave, lane = output feature; writes split tables
__global__ void __launch_bounds__(256)
gemm_kernel(const unsigned short* __restrict__ Y, const float* __restrict__ W,
            const float* __restrict__ b, const float* __restrict__ pa,
            const float* __restrict__ dinv,
            unsigned short* __restrict__ XsLn, unsigned short* __restrict__ XsHn, int n) {
    __shared__ float Wl[D * D];
    int t = threadIdx.x;
    for (int i = t; i < D * D; i += 256) Wl[i] = W[i];
    __syncthreads();
    int wid = t >> 6, lane = t & 63;
    int nodeA = blockIdx.x * 8 + wid * 2;
    int nodeB = nodeA + 1;
    if (nodeA >= n) return;
    bool vB = (nodeB < n);
    float yA = bfbits2f(Y[(size_t)nodeA * D + lane]);
    float yB = vB ? bfbits2f(Y[(size_t)nodeB * D + lane]) : 0.f;
    float dnA = dinv[nodeA], dnB = vB ? dinv[nodeB] : 0.f;
    float bl = b[lane];
    float pr = pa[0];
    float a0 = 0.f, a1 = 0.f, b0 = 0.f, b1 = 0.f;
#pragma unroll
    for (int k = 0; k < D; k += 2) {
        float w0 = Wl[(k    ) * D + lane];
        float w1 = Wl[(k + 1) * D + lane];
        float xa0 = __shfl(yA, k,     64);
        float xb0 = __shfl(yB, k,     64);
        float xa1 = __shfl(yA, k + 1, 64);
        float xb1 = __shfl(yB, k + 1, 64);
        a0 = fmaf(xa0, w0, a0);
        b0 = fmaf(xb0, w0, b0);
        a1 = fmaf(xa1, w1, a1);
        b1 = fmaf(xb1, w1, b1);
    }
    float accA = a0 + a1 + bl;
    float accB = b0 + b1 + bl;
    accA = (accA >= 0.f) ? accA : pr * accA;
    accB = (accB >= 0.f) ? accB : pr * accB;
    accA *= dnA; accB *= dnB;                // prescale for next layer
    int half = lane >> 5, off = lane & 31;
    unsigned short* dstT = half ? XsHn : XsLn;
    dstT[(size_t)nodeA * HW + off] = f2bfbits(accA);
    if (vB) dstT[(size_t)nodeB * HW + off] = f2bfbits(accB);
}

// layer-3: GEMM + LayerNorm + output write
__global__ void __launch_bounds__(256)
gemm_ln_kernel(const unsigned short* __restrict__ Y, const float* __restrict__ W,
               const float* __restrict__ b, const float* __restrict__ g,
               const float* __restrict__ be, const int* __restrict__ flag,
               void* __restrict__ out, int n) {
    __shared__ float Wl[D * D];
    int t = threadIdx.x;
    for (int i = t; i < D * D; i += 256) Wl[i] = W[i];
    __syncthreads();
    int wid = t >> 6, lane = t & 63;
    int nodeA = blockIdx.x * 8 + wid * 2;
    int nodeB = nodeA + 1;
    if (nodeA >= n) return;
    bool vB = (nodeB < n);
    float yA = bfbits2f(Y[(size_t)nodeA * D + lane]);
    float yB = vB ? bfbits2f(Y[(size_t)nodeB * D + lane]) : 0.f;
    int   isf = *flag;
    float bl  = b[lane];
    float gl  = g[lane];
    float bel = be[lane];
    float a0 = 0.f, a1 = 0.f, b0 = 0.f, b1 = 0.f;
#pragma unroll
    for (int k = 0; k < D; k += 2) {
        float w0 = Wl[(k    ) * D + lane];
        float w1 = Wl[(k + 1) * D + lane];
        float xa0 = __shfl(yA, k,     64);
        float xb0 = __shfl(yB, k,     64);
        float xa1 = __shfl(yA, k + 1, 64);
        float xb1 = __shfl(yB, k + 1, 64);
        a0 = fmaf(xa0, w0, a0);
        b0 = fmaf(xb0, w0, b0);
        a1 = fmaf(xa1, w1, a1);
        b1 = fmaf(xb1, w1, b1);
    }
    float accA = a0 + a1 + bl;
    float accB = b0 + b1 + bl;
    float sA = accA, sB = accB;
#pragma unroll
    for (int off = 32; off > 0; off >>= 1) { sA += __shfl_xor(sA, off, 64); sB += __shfl_xor(sB, off, 64); }
    float dA = accA - sA * (1.f / 64.f), dB = accB - sB * (1.f / 64.f);
    float vA2 = dA * dA, vB2 = dB * dB;
#pragma unroll
    for (int off = 32; off > 0; off >>= 1) { vA2 += __shfl_xor(vA2, off, 64); vB2 += __shfl_xor(vB2, off, 64); }
    float rA = rsqrtf(vA2 * (1.f / 64.f) + 1e-5f);
    float rB = rsqrtf(vB2 * (1.f / 64.f) + 1e-5f);
    float oA = dA * rA * gl + bel;
    float oB = dB * rB * gl + bel;
    size_t oiA = (size_t)nodeA * D + lane;
    size_t oiB = (size_t)nodeB * D + lane;
    if (isf) {
        ((float*)out)[oiA] = oA;
        if (vB) ((float*)out)[oiB] = oB;
    } else {
        ((unsigned short*)out)[oiA] = f2bfbits(oA);
        if (vB) ((unsigned short*)out)[oiB] = f2bfbits(oB);
    }
}

// ---- driver ----------------------------------------------------------------

extern "C" void kernel_launch(void* const* d_in, const int* in_sizes, int n_in,
                              void* d_out, int out_size, void* d_ws, size_t ws_size,
                              hipStream_t stream) {
    const void* X   = d_in[0];
    const void* W1  = d_in[1];
    const void* b1  = d_in[2];
    const void* W2  = d_in[3];
    const void* b2  = d_in[4];
    const void* W3  = d_in[5];
    const void* b3  = d_in[6];
    const void* pa  = d_in[7];
    const void* g   = d_in[8];
    const void* be  = d_in[9];
    const int*  ei  = (const int*)d_in[10];

    int N = in_sizes[0] / D;
    int E = in_sizes[10] / 2;
    int NB = (N + 63) >> BK_SHIFT;   // <= 1024 for N <= 65536
    int CH = (E + NBLK - 1) / NBLK;  // edges per radix block
    const int* src = ei;
    const int* dst = ei + E;

    char* p = (char*)d_ws;
    auto alloc = [&](size_t bytes) { void* q = (void*)p; p += (bytes + 255) & ~(size_t)255; return q; };
    int*            flag       = (int*)alloc(4);
    int*            H          = (int*)alloc((size_t)1024 * NBLK * 4);
    int*            T          = (int*)alloc(1024 * 4);
    int*            bucket_beg = (int*)alloc(1025 * 4);
    int*            row_beg    = (int*)alloc((size_t)N * 4);
    int*            cnt        = (int*)alloc((size_t)N * 4);
    float*          dinv       = (float*)alloc((size_t)N * 4);
    int*            col        = (int*)alloc(((size_t)E + (size_t)NB * PAD_SLACK) * 4);
    unsigned int*   tmp        = (unsigned int*)alloc((size_t)E * 4);
    float*          P          = (float*)alloc((size_t)(OPA + 1) * 4);
    unsigned short* XsL1       = (unsigned short*)alloc((size_t)(N + 1) * HW * 2);
    unsigned short* XsH1       = (unsigned short*)alloc((size_t)(N + 1) * HW * 2);
    unsigned short* XsL2       = (unsigned short*)alloc((size_t)(N + 1) * HW * 2);
    unsigned short* XsH2       = (unsigned short*)alloc((size_t)(N + 1) * HW * 2);
    unsigned short* Y          = (unsigned short*)alloc((size_t)N * D * 2);
    (void)ws_size; (void)n_in; (void)out_size;

    sniff_kernel<<<1, 64, 0, stream>>>((const unsigned short*)W1, flag);
    cvt_params_kernel<<<1, 256, 0, stream>>>(W1, b1, W2, b2, W3, b3, pa, g, be, flag, P);

    binA1_kernel<<<NBLK, 256, 0, stream>>>(dst, E, NB, CH, H);
    binA2_kernel<<<NB, 256, 0, stream>>>(H, T);
    binA3_kernel<<<1, 1024, 0, stream>>>(T, bucket_beg, NB, XsL1, XsH1, XsL2, XsH2, N);
    binA4_kernel<<<NBLK, 256, 0, stream>>>(src, dst, H, bucket_beg, tmp, E, NB, CH);
    binB_kernel<<<NB, 256, 0, stream>>>(tmp, bucket_beg, row_beg, cnt, dinv, col, X, flag, XsL1, XsH1, N);

    int ngb = (N + 7) / 8;           // 8 nodes per 256-thread block (2 per wave)

    // layer 1
    agg_half_kernel<<<ngb, 256, 0, stream>>>(XsL1, row_beg, cnt, col, dinv, Y,      N);
    agg_half_kernel<<<ngb, 256, 0, stream>>>(XsH1, row_beg, cnt, col, dinv, Y + HW, N);
    gemm_kernel<<<ngb, 256, 0, stream>>>(Y, P + OW1, P + OB1, P + OPA, dinv, XsL2, XsH2, N);
    // layer 2
    agg_half_kernel<<<ngb, 256, 0, stream>>>(XsL2, row_beg, cnt, col, dinv, Y,      N);
    agg_half_kernel<<<ngb, 256, 0, stream>>>(XsH2, row_beg, cnt, col, dinv, Y + HW, N);
    gemm_kernel<<<ngb, 256, 0, stream>>>(Y, P + OW2, P + OB2, P + OPA, dinv, XsL1, XsH1, N);
    // layer 3
    agg_half_kernel<<<ngb, 256, 0, stream>>>(XsL1, row_beg, cnt, col, dinv, Y,      N);
    agg_half_kernel<<<ngb, 256, 0, stream>>>(XsH1, row_beg, cnt, col, dinv, Y + HW, N);
    gemm_ln_kernel<<<ngb, 256, 0, stream>>>(Y, P + OW3, P + OB3, P + OG, P + OBE, flag, d_out, N);
}

// Round 15
// 408.209 us; speedup vs baseline: 1.0169x; 1.0169x over previous
//
#include <hip/hip_runtime.h>

#define D 64
#define HW 32                   // half-width features
#define BK_SHIFT 6              // 64 nodes per bucket
#define BK_CAP 8192             // staged entries per bucket (mean ~1600)
#define NBLK 256                // radix pass blocks
#define PAD_SLACK 2048          // per-bucket col padding slack (64 nodes * <=32)

typedef unsigned int v4u __attribute__((ext_vector_type(4)));

__device__ __forceinline__ float bfbits2f(unsigned short b) {
    union { unsigned int u; float f; } c;
    c.u = ((unsigned int)b) << 16;
    return c.f;
}

__device__ __forceinline__ unsigned short f2bfbits(float f) {
    union { float f; unsigned int u; } c;
    c.f = f;
    unsigned int u = c.u;
    unsigned int lsb = (u >> 16) & 1u;
    u += 0x7fffu + lsb;           // round-to-nearest-even
    return (unsigned short)(u >> 16);
}

__device__ __forceinline__ float ldmix(const void* p, size_t i, int isf32) {
    return isf32 ? ((const float*)p)[i] : bfbits2f(((const unsigned short*)p)[i]);
}

// ---- dtype sniff -----------------------------------------------------------
__global__ void sniff_kernel(const unsigned short* __restrict__ W, int* __restrict__ flag) {
    int t = threadIdx.x;
    bool bad = false;
    for (int i = t; i < 256; i += 64) {
        float v = bfbits2f(W[i]);
        if (!(v == v) || fabsf(v) > 1e4f) bad = true;
    }
    unsigned long long m = __ballot(bad);
    if (t == 0) *flag = (m != 0ull) ? 1 : 0;
}

// ---- param conversion ------------------------------------------------------
#define OW1 0
#define OW2 4096
#define OW3 8192
#define OB1 12288
#define OB2 12352
#define OB3 12416
#define OG  12480
#define OBE 12544
#define OPA 12608

__global__ void cvt_params_kernel(const void* W1, const void* b1, const void* W2, const void* b2,
                                  const void* W3, const void* b3, const void* pa, const void* g,
                                  const void* be, const int* __restrict__ flag,
                                  float* __restrict__ P) {
    int isf = *flag;
    int t = threadIdx.x;                 // one block of 256
    for (int i = t; i < D * D; i += 256) {
        P[OW1 + i] = ldmix(W1, i, isf);
        P[OW2 + i] = ldmix(W2, i, isf);
        P[OW3 + i] = ldmix(W3, i, isf);
    }
    if (t < D) {
        P[OB1 + t] = ldmix(b1, t, isf);
        P[OB2 + t] = ldmix(b2, t, isf);
        P[OB3 + t] = ldmix(b3, t, isf);
        P[OG  + t] = ldmix(g,  t, isf);
        P[OBE + t] = ldmix(be, t, isf);
    }
    if (t == 0) P[OPA] = ldmix(pa, 0, isf);
}

// ---- deterministic two-pass radix binning (no global atomics) --------------
// H layout: H[bucket * NBLK + block]

__global__ void binA1_kernel(const int* __restrict__ dst, int E, int NB, int CH,
                             int* __restrict__ H) {
    __shared__ int h[1024];
    int t = threadIdx.x, bb = blockIdx.x;
    for (int i = t; i < NB; i += 256) h[i] = 0;
    __syncthreads();
    int beg = bb * CH, end = beg + CH; if (end > E) end = E;
    for (int e = beg + t; e < end; e += 256)
        atomicAdd(&h[dst[e] >> BK_SHIFT], 1);
    __syncthreads();
    for (int i = t; i < NB; i += 256) H[i * NBLK + bb] = h[i];
}

// per-bucket exclusive scan of the NBLK block-counts; T[b] = bucket total
__global__ void binA2_kernel(int* __restrict__ H, int* __restrict__ T) {
    __shared__ int ws[4];
    __shared__ int wx[4];
    int b = blockIdx.x, t = threadIdx.x;
    int lane = t & 63, wid = t >> 6;
    int v = H[b * NBLK + t];
    int incl = v;
#pragma unroll
    for (int off = 1; off < 64; off <<= 1) {
        int u = __shfl_up(incl, off, 64);
        if (lane >= off) incl += u;
    }
    if (lane == 63) ws[wid] = incl;
    __syncthreads();
    if (t == 0) {
        int s = 0;
#pragma unroll
        for (int j = 0; j < 4; ++j) { wx[j] = s; s += ws[j]; }
        T[b] = s;
    }
    __syncthreads();
    H[b * NBLK + t] = wx[wid] + incl - v;
}

// single-block scan of bucket totals -> bucket_beg; also zero-rows of tables
__global__ void binA3_kernel(const int* __restrict__ T, int* __restrict__ bucket_beg, int NB,
                             unsigned short* XsL1, unsigned short* XsH1,
                             unsigned short* XsL2, unsigned short* XsH2, int N) {
    __shared__ int tile[1024];
    int t = threadIdx.x;
    int v = (t < NB) ? T[t] : 0;
    tile[t] = v;
    __syncthreads();
    for (int off = 1; off < 1024; off <<= 1) {
        int add = (t >= off) ? tile[t - off] : 0;
        __syncthreads();
        tile[t] += add;
        __syncthreads();
    }
    if (t < NB) bucket_beg[t] = tile[t] - v;
    if (t == NB - 1) bucket_beg[NB] = tile[t];
    if (t < HW) {                            // zero row (index N) for pad edges
        XsL1[(size_t)N * HW + t] = 0;
        XsH1[(size_t)N * HW + t] = 0;
        XsL2[(size_t)N * HW + t] = 0;
        XsH2[(size_t)N * HW + t] = 0;
    }
}

// scatter edges into bucket-grouped tmp via LDS cursors (deterministic ranges)
__global__ void binA4_kernel(const int* __restrict__ src, const int* __restrict__ dst,
                             const int* __restrict__ H, const int* __restrict__ bucket_beg,
                             unsigned int* __restrict__ tmp, int E, int NB, int CH) {
    __shared__ int O[1024];
    int t = threadIdx.x, bb = blockIdx.x;
    for (int i = t; i < NB; i += 256) O[i] = bucket_beg[i] + H[i * NBLK + bb];
    __syncthreads();
    int beg = bb * CH, end = beg + CH; if (end > E) end = E;
    for (int e = beg + t; e < end; e += 256) {
        int d = dst[e];
        int p = atomicAdd(&O[d >> BK_SHIFT], 1);
        tmp[p] = ((unsigned int)src[e] << BK_SHIFT) | (unsigned int)(d & 63);
    }
}

// one block per bucket: per-node count + padded scan (self-slot + mult-32) +
// L2-local scatter + pad fill (first pad = SELF loop, rest = zero row N) +
// fused layer-1 prescale into split half-tables
__global__ void binB_kernel(const unsigned int* __restrict__ tmp, const int* __restrict__ bucket_beg,
                            int* __restrict__ row_beg, int* __restrict__ cnt,
                            float* __restrict__ dinv, int* __restrict__ col,
                            const void* __restrict__ X, const int* __restrict__ flag,
                            unsigned short* __restrict__ XsL, unsigned short* __restrict__ XsH,
                            int N) {
    __shared__ unsigned int ent[BK_CAP];
    __shared__ int lv[64], lpv[64], lpe[64], lcur[64];
    __shared__ float ldv[64];
    int b = blockIdx.x, t = threadIdx.x;
    int beg = bucket_beg[b], end = bucket_beg[b + 1];
    int colbase = beg + b * PAD_SLACK;
    int m = end - beg;
    bool staged = (m <= BK_CAP);
    if (t < 64) lv[t] = 0;
    __syncthreads();
    for (int i = t; i < m; i += 256) {
        unsigned int e = tmp[beg + i];
        if (staged) ent[i] = e;
        atomicAdd(&lv[e & 63u], 1);
    }
    __syncthreads();
    if (t < 64) {
        int v  = lv[t];
        int pv = (v + 1 + 31) & ~31;         // +1 self slot, padded to mult of 32
        int incl = pv;
#pragma unroll
        for (int off = 1; off < 64; off <<= 1) {
            int u = __shfl_up(incl, off, 64);
            if (t >= off) incl += u;
        }
        int pexcl = incl - pv;
        lpv[t]  = pv;
        lpe[t]  = pexcl;
        lcur[t] = pexcl;
        float dv = rsqrtf((float)(v + 1));
        ldv[t] = dv;
        int node = b * 64 + t;
        if (node < N) {
            row_beg[node] = colbase + pexcl;
            cnt[node]     = pv;              // padded count incl. self (loop bound)
            dinv[node]    = dv;
        }
    }
    __syncthreads();
    for (int i = t; i < m; i += 256) {
        unsigned int e = staged ? ent[i] : tmp[beg + i];
        int p = atomicAdd(&lcur[e & 63u], 1);
        col[colbase + p] = (int)(e >> BK_SHIFT);
    }
    // pad fill: slot v = SELF node (replaces explicit self-loop), rest zero row N
    for (int i = t; i < 64 * 32; i += 256) {
        int nl = i >> 5, j = i & 31;
        int idx = lv[nl] + j;
        if (idx < lpv[nl]) {
            int node = b * 64 + nl;
            col[colbase + lpe[nl] + idx] = (j == 0) ? node : N;
        }
    }
    // fused layer-1 prescale into split tables
    int isf = *flag;
    for (int i = t; i < 64 * 64; i += 256) {
        int nl = i >> 6, f = i & 63;
        int node = b * 64 + nl;
        if (node < N) {
            unsigned short v16 = f2bfbits(ldv[nl] * ldmix(X, (size_t)node * D + f, isf));
            if (f < HW) XsL[(size_t)node * HW + f] = v16;
            else        XsH[(size_t)node * HW + (f - HW)] = v16;
        }
    }
}

// ---- feature kernels -------------------------------------------------------

__device__ __forceinline__ void acc8(float* a, v4u v) {
    a[0] += bfbits2f((unsigned short)(v.x & 0xffffu));
    a[1] += bfbits2f((unsigned short)(v.x >> 16));
    a[2] += bfbits2f((unsigned short)(v.y & 0xffffu));
    a[3] += bfbits2f((unsigned short)(v.y >> 16));
    a[4] += bfbits2f((unsigned short)(v.z & 0xffffu));
    a[5] += bfbits2f((unsigned short)(v.z >> 16));
    a[6] += bfbits2f((unsigned short)(v.w & 0xffffu));
    a[7] += bfbits2f((unsigned short)(v.w >> 16));
}

// 64B-row load from a half-table (plain: this is the L2-resident reuse data)
__device__ __forceinline__ v4u ldrow32(const unsigned short* __restrict__ Xt, int s, int sub) {
    return *((const v4u*)(Xt + ((size_t)s << 5)) + sub);
}

// shared half-gather core: 2 nodes/wave, 16 rows per load inst (4 lanes/row).
// After reduction every lane holds a[j] = sum of H-feat (lane&3)*8+j.
__device__ __forceinline__ void gather_half(const unsigned short* __restrict__ Xt,
                                            int begA, int pcA, int begB, int pcB,
                                            const int* __restrict__ col,
                                            int lane, float* __restrict__ a, float* __restrict__ b) {
    int sub = lane & 3, slot = lane >> 2;
#pragma unroll
    for (int j = 0; j < 8; ++j) { a[j] = 0.f; b[j] = 0.f; }
    {
        const int* cA = col + begA;
        const int* cB = col + begB;
        int sA0 = cA[slot];
        int sA1 = cA[16 + slot];
        int sB0 = cB[slot];
        int sB1 = cB[16 + slot];
        v4u vA0 = ldrow32(Xt, sA0, sub);
        v4u vA1 = ldrow32(Xt, sA1, sub);
        v4u vB0 = ldrow32(Xt, sB0, sub);
        v4u vB1 = ldrow32(Xt, sB1, sub);
        acc8(a, vA0); acc8(a, vA1);
        acc8(b, vB0); acc8(b, vB1);
    }
    for (int c = 32; c < pcA; c += 32) {
        const int* cA = col + begA + c;
        int s0 = cA[slot];
        int s1 = cA[16 + slot];
        v4u v0 = ldrow32(Xt, s0, sub);
        v4u v1 = ldrow32(Xt, s1, sub);
        acc8(a, v0); acc8(a, v1);
    }
    for (int c = 32; c < pcB; c += 32) {
        const int* cB = col + begB + c;
        int s0 = cB[slot];
        int s1 = cB[16 + slot];
        v4u v0 = ldrow32(Xt, s0, sub);
        v4u v1 = ldrow32(Xt, s1, sub);
        acc8(b, v0); acc8(b, v1);
    }
#pragma unroll
    for (int off = 4; off < 64; off <<= 1) {
#pragma unroll
        for (int j = 0; j < 8; ++j) {
            a[j] += __shfl_xor(a[j], off, 64);
            b[j] += __shfl_xor(b[j], off, 64);
        }
    }
}

// L-half aggregation -> dense YL (64B bf16 rows, dn applied)
__global__ void __launch_bounds__(256)
aggL_kernel(const unsigned short* __restrict__ Xt,
            const int* __restrict__ row_beg, const int* __restrict__ cnt,
            const int* __restrict__ col, const float* __restrict__ dinv,
            unsigned short* __restrict__ YL, int n) {
    int t = threadIdx.x;
    int wid = t >> 6, lane = t & 63;
    int sub = lane & 3, slot = lane >> 2;
    int nodeA = blockIdx.x * 8 + wid * 2;
    int nodeB = nodeA + 1;
    if (nodeA >= n) return;
    bool vB = (nodeB < n);
    int begA = row_beg[nodeA], pcA = cnt[nodeA];
    int begB = vB ? row_beg[nodeB] : begA, pcB = vB ? cnt[nodeB] : 32;
    float dnA = dinv[nodeA], dnB = vB ? dinv[nodeB] : 0.f;
    float a[8], b[8];
    gather_half(Xt, begA, pcA, begB, pcB, col, lane, a, b);
    const float* sel = (slot == 1) ? b : a;
    float dn = (slot == 1) ? dnB : dnA;
    unsigned int pw[4];
#pragma unroll
    for (int j = 0; j < 4; ++j)
        pw[j] = (unsigned int)f2bfbits(dn * sel[2 * j]) |
                ((unsigned int)f2bfbits(dn * sel[2 * j + 1]) << 16);
    v4u w; w.x = pw[0]; w.y = pw[1]; w.z = pw[2]; w.w = pw[3];
    if (slot == 0)
        *((v4u*)(YL + ((size_t)nodeA << 5)) + sub) = w;
    else if (slot == 1 && vB)
        *((v4u*)(YL + ((size_t)nodeB << 5)) + sub) = w;
}

// H-half aggregation + fused GEMM (+PReLU+prescale): GEMM shuffles hide under
// the gather latency of co-resident waves (the r14 standalone gemm was
// LDS-pipe-bound at 56us because nothing hid it).
__global__ void __launch_bounds__(256)
aggHG_kernel(const unsigned short* __restrict__ XtH, const unsigned short* __restrict__ YL,
             const int* __restrict__ row_beg, const int* __restrict__ cnt,
             const int* __restrict__ col, const float* __restrict__ dinv,
             const float* __restrict__ W, const float* __restrict__ bb,
             const float* __restrict__ pa,
             unsigned short* __restrict__ XsLn, unsigned short* __restrict__ XsHn, int n) {
    __shared__ float Wl[D * D];
    int t = threadIdx.x;
    for (int i = t; i < D * D; i += 256) Wl[i] = W[i];
    __syncthreads();
    int wid = t >> 6, lane = t & 63;
    int nodeA = blockIdx.x * 8 + wid * 2;
    int nodeB = nodeA + 1;
    if (nodeA >= n) return;
    bool vB = (nodeB < n);
    int begA = row_beg[nodeA], pcA = cnt[nodeA];
    int begB = vB ? row_beg[nodeB] : begA, pcB = vB ? cnt[nodeB] : 32;
    float dnA = dinv[nodeA], dnB = vB ? dinv[nodeB] : 0.f;
    // L-half x from YL: lanes 0..31 -> nodeA feats, 32..63 -> nodeB feats
    int nodeY = (lane < 32) ? nodeA : (vB ? nodeB : nodeA);
    float yl = bfbits2f(YL[(size_t)nodeY * HW + (lane & 31)]);
    float bl = bb[lane];
    float pr = pa[0];
    float a[8], b[8];
    gather_half(XtH, begA, pcA, begB, pcB, col, lane, a, b);
    float xha[8], xhb[8];
#pragma unroll
    for (int j = 0; j < 8; ++j) { xha[j] = dnA * a[j]; xhb[j] = dnB * b[j]; }
    // GEMM: k<32 from YL, k>=32 from H regs (feat f=k-32 lives in lane f>>3, elem f&7)
    float a0 = 0.f, a1 = 0.f, b0 = 0.f, b1 = 0.f;
#pragma unroll
    for (int k = 0; k < 32; k += 2) {
        float w0 = Wl[(k    ) * D + lane];
        float w1 = Wl[(k + 1) * D + lane];
        a0 = fmaf(__shfl(yl, k,      64), w0, a0);
        b0 = fmaf(__shfl(yl, 32 + k, 64), w0, b0);
        a1 = fmaf(__shfl(yl, k + 1,      64), w1, a1);
        b1 = fmaf(__shfl(yl, 32 + k + 1, 64), w1, b1);
    }
#pragma unroll
    for (int k = 32; k < 64; k += 2) {
        int f0 = k - 32, f1 = k - 31;
        float w0 = Wl[(k    ) * D + lane];
        float w1 = Wl[(k + 1) * D + lane];
        a0 = fmaf(__shfl(xha[f0 & 7], f0 >> 3, 64), w0, a0);
        b0 = fmaf(__shfl(xhb[f0 & 7], f0 >> 3, 64), w0, b0);
        a1 = fmaf(__shfl(xha[f1 & 7], f1 >> 3, 64), w1, a1);
        b1 = fmaf(__shfl(xhb[f1 & 7], f1 >> 3, 64), w1, b1);
    }
    float accA = a0 + a1 + bl;
    float accB = b0 + b1 + bl;
    accA = (accA >= 0.f) ? accA : pr * accA;
    accB = (accB >= 0.f) ? accB : pr * accB;
    accA *= dnA; accB *= dnB;                // prescale for next layer
    int half = lane >> 5, off = lane & 31;
    unsigned short* dstT = half ? XsHn : XsLn;
    dstT[(size_t)nodeA * HW + off] = f2bfbits(accA);
    if (vB) dstT[(size_t)nodeB * HW + off] = f2bfbits(accB);
}

// layer-3 variant: fused GEMM + LayerNorm + output write
__global__ void __launch_bounds__(256)
aggHG_ln_kernel(const unsigned short* __restrict__ XtH, const unsigned short* __restrict__ YL,
                const int* __restrict__ row_beg, const int* __restrict__ cnt,
                const int* __restrict__ col, const float* __restrict__ dinv,
                const float* __restrict__ W, const float* __restrict__ bb,
                const float* __restrict__ g, const float* __restrict__ be,
                const int* __restrict__ flag, void* __restrict__ out, int n) {
    __shared__ float Wl[D * D];
    int t = threadIdx.x;
    for (int i = t; i < D * D; i += 256) Wl[i] = W[i];
    __syncthreads();
    int wid = t >> 6, lane = t & 63;
    int nodeA = blockIdx.x * 8 + wid * 2;
    int nodeB = nodeA + 1;
    if (nodeA >= n) return;
    bool vB = (nodeB < n);
    int begA = row_beg[nodeA], pcA = cnt[nodeA];
    int begB = vB ? row_beg[nodeB] : begA, pcB = vB ? cnt[nodeB] : 32;
    float dnA = dinv[nodeA], dnB = vB ? dinv[nodeB] : 0.f;
    int nodeY = (lane < 32) ? nodeA : (vB ? nodeB : nodeA);
    float yl = bfbits2f(YL[(size_t)nodeY * HW + (lane & 31)]);
    int   isf = *flag;
    float bl  = bb[lane];
    float gl  = g[lane];
    float bel = be[lane];
    float a[8], b[8];
    gather_half(XtH, begA, pcA, begB, pcB, col, lane, a, b);
    float xha[8], xhb[8];
#pragma unroll
    for (int j = 0; j < 8; ++j) { xha[j] = dnA * a[j]; xhb[j] = dnB * b[j]; }
    float a0 = 0.f, a1 = 0.f, b0 = 0.f, b1 = 0.f;
#pragma unroll
    for (int k = 0; k < 32; k += 2) {
        float w0 = Wl[(k    ) * D + lane];
        float w1 = Wl[(k + 1) * D + lane];
        a0 = fmaf(__shfl(yl, k,      64), w0, a0);
        b0 = fmaf(__shfl(yl, 32 + k, 64), w0, b0);
        a1 = fmaf(__shfl(yl, k + 1,      64), w1, a1);
        b1 = fmaf(__shfl(yl, 32 + k + 1, 64), w1, b1);
    }
#pragma unroll
    for (int k = 32; k < 64; k += 2) {
        int f0 = k - 32, f1 = k - 31;
        float w0 = Wl[(k    ) * D + lane];
        float w1 = Wl[(k + 1) * D + lane];
        a0 = fmaf(__shfl(xha[f0 & 7], f0 >> 3, 64), w0, a0);
        b0 = fmaf(__shfl(xhb[f0 & 7], f0 >> 3, 64), w0, b0);
        a1 = fmaf(__shfl(xha[f1 & 7], f1 >> 3, 64), w1, a1);
        b1 = fmaf(__shfl(xhb[f1 & 7], f1 >> 3, 64), w1, b1);
    }
    float accA = a0 + a1 + bl;
    float accB = b0 + b1 + bl;
    float sA = accA, sB = accB;
#pragma unroll
    for (int off = 32; off > 0; off >>= 1) { sA += __shfl_xor(sA, off, 64); sB += __shfl_xor(sB, off, 64); }
    float dA = accA - sA * (1.f / 64.f), dB = accB - sB * (1.f / 64.f);
    float vA2 = dA * dA, vB2 = dB * dB;
#pragma unroll
    for (int off = 32; off > 0; off >>= 1) { vA2 += __shfl_xor(vA2, off, 64); vB2 += __shfl_xor(vB2, off, 64); }
    float rA = rsqrtf(vA2 * (1.f / 64.f) + 1e-5f);
    float rB = rsqrtf(vB2 * (1.f / 64.f) + 1e-5f);
    float oA = dA * rA * gl + bel;
    float oB = dB * rB * gl + bel;
    size_t oiA = (size_t)nodeA * D + lane;
    size_t oiB = (size_t)nodeB * D + lane;
    if (isf) {
        ((float*)out)[oiA] = oA;
        if (vB) ((float*)out)[oiB] = oB;
    } else {
        ((unsigned short*)out)[oiA] = f2bfbits(oA);
        if (vB) ((unsigned short*)out)[oiB] = f2bfbits(oB);
    }
}

// ---- driver ----------------------------------------------------------------

extern "C" void kernel_launch(void* const* d_in, const int* in_sizes, int n_in,
                              void* d_out, int out_size, void* d_ws, size_t ws_size,
                              hipStream_t stream) {
    const void* X   = d_in[0];
    const void* W1  = d_in[1];
    const void* b1  = d_in[2];
    const void* W2  = d_in[3];
    const void* b2  = d_in[4];
    const void* W3  = d_in[5];
    const void* b3  = d_in[6];
    const void* pa  = d_in[7];
    const void* g   = d_in[8];
    const void* be  = d_in[9];
    const int*  ei  = (const int*)d_in[10];

    int N = in_sizes[0] / D;
    int E = in_sizes[10] / 2;
    int NB = (N + 63) >> BK_SHIFT;   // <= 1024 for N <= 65536
    int CH = (E + NBLK - 1) / NBLK;  // edges per radix block
    const int* src = ei;
    const int* dst = ei + E;

    char* p = (char*)d_ws;
    auto alloc = [&](size_t bytes) { void* q = (void*)p; p += (bytes + 255) & ~(size_t)255; return q; };
    int*            flag       = (int*)alloc(4);
    int*            H          = (int*)alloc((size_t)1024 * NBLK * 4);
    int*            T          = (int*)alloc(1024 * 4);
    int*            bucket_beg = (int*)alloc(1025 * 4);
    int*            row_beg    = (int*)alloc((size_t)N * 4);
    int*            cnt        = (int*)alloc((size_t)N * 4);
    float*          dinv       = (float*)alloc((size_t)N * 4);
    int*            col        = (int*)alloc(((size_t)E + (size_t)NB * PAD_SLACK) * 4);
    unsigned int*   tmp        = (unsigned int*)alloc((size_t)E * 4);
    float*          P          = (float*)alloc((size_t)(OPA + 1) * 4);
    unsigned short* XsL1       = (unsigned short*)alloc((size_t)(N + 1) * HW * 2);
    unsigned short* XsH1       = (unsigned short*)alloc((size_t)(N + 1) * HW * 2);
    unsigned short* XsL2       = (unsigned short*)alloc((size_t)(N + 1) * HW * 2);
    unsigned short* XsH2       = (unsigned short*)alloc((size_t)(N + 1) * HW * 2);
    unsigned short* YL         = (unsigned short*)alloc((size_t)N * HW * 2);
    (void)ws_size; (void)n_in; (void)out_size;

    sniff_kernel<<<1, 64, 0, stream>>>((const unsigned short*)W1, flag);
    cvt_params_kernel<<<1, 256, 0, stream>>>(W1, b1, W2, b2, W3, b3, pa, g, be, flag, P);

    binA1_kernel<<<NBLK, 256, 0, stream>>>(dst, E, NB, CH, H);
    binA2_kernel<<<NB, 256, 0, stream>>>(H, T);
    binA3_kernel<<<1, 1024, 0, stream>>>(T, bucket_beg, NB, XsL1, XsH1, XsL2, XsH2, N);
    binA4_kernel<<<NBLK, 256, 0, stream>>>(src, dst, H, bucket_beg, tmp, E, NB, CH);
    binB_kernel<<<NB, 256, 0, stream>>>(tmp, bucket_beg, row_beg, cnt, dinv, col, X, flag, XsL1, XsH1, N);

    int ngb = (N + 7) / 8;           // 8 nodes per 256-thread block (2 per wave)

    // layer 1
    aggL_kernel <<<ngb, 256, 0, stream>>>(XsL1, row_beg, cnt, col, dinv, YL, N);
    aggHG_kernel<<<ngb, 256, 0, stream>>>(XsH1, YL, row_beg, cnt, col, dinv, P + OW1, P + OB1, P + OPA, XsL2, XsH2, N);
    // layer 2
    aggL_kernel <<<ngb, 256, 0, stream>>>(XsL2, row_beg, cnt, col, dinv, YL, N);
    aggHG_kernel<<<ngb, 256, 0, stream>>>(XsH2, YL, row_beg, cnt, col, dinv, P + OW2, P + OB2, P + OPA, XsL1, XsH1, N);
    // layer 3
    aggL_kernel <<<ngb, 256, 0, stream>>>(XsL1, row_beg, cnt, col, dinv, YL, N);
    aggHG_ln_kernel<<<ngb, 256, 0, stream>>>(XsH1, YL, row_beg, cnt, col, dinv, P + OW3, P + OB3, P + OG, P + OBE, flag, d_out, N);
}